// Round 17
// baseline (699.927 us; speedup 1.0000x reference)
//
#include <hip/hip_runtime.h>
#include <hip/hip_bf16.h>

// ---------------- problem constants ----------------
constexpr int N_NEWS = 50000, N_KW = 10000, N_ST = 2000;
constexpr int F_NEWS = 768, F_KW = 128, F_ST = 64;
constexpr int HID = 256, OUTD = 128;
constexpr int E_HK = 500000, E_HS = 250000, E_LBL = 150000;

// CSR section offsets in the concatenated degree/cursor pools
constexpr int OFFA = 0;                    // e_hk keyed by dst (kw)
constexpr int OFFB = N_KW;                 // e_hs keyed by dst (st)
constexpr int OFFC = N_KW + N_ST;          // e_hk keyed by src (news)
constexpr int OFFD = OFFC + N_NEWS;        // e_hs keyed by src (news)
constexpr int NTOT = OFFD + N_NEWS;        // 112000

enum { FLAG_ACC = 1, FLAG_RELU = 2 };

typedef unsigned short u16;
typedef __attribute__((ext_vector_type(8))) short bf16x8;
typedef __attribute__((ext_vector_type(8))) unsigned short u16x8;
typedef __attribute__((ext_vector_type(4))) float f32x4;

__device__ __forceinline__ u16 f2bf(float x) {
    return __builtin_bit_cast(u16, __float2bfloat16(x));
}
__device__ __forceinline__ float bf2f(u16 h) {
    unsigned u = ((unsigned)h) << 16;
    return __builtin_bit_cast(float, u);
}
__device__ __forceinline__ void split2(float x, u16& h, u16& l) {
    h = f2bf(x);
    l = f2bf(x - bf2f(h));
}

// async global->LDS DMA, 16B per lane; LDS dest = wave-uniform base + lane*16
__device__ __forceinline__ void gload16(const void* g, void* s) {
    __builtin_amdgcn_global_load_lds(
        (const __attribute__((address_space(1))) void*)g,
        (__attribute__((address_space(3))) void*)s, 16, 0, 0);
}

// ---------------- split-bf16 MFMA GEMM, dbuf LDS + COUNTED-vmcnt pipeline (T3+T4) ------
// ASRC: 0 = fp32 A (DMA fp32, split in regs), 1 = plane A, 2 = dual-table plane A
// WMODE: 1 = hi-only C write, 2 = fused decoder reduce -> outv
// PREC: 3 = full split (3 MFMA), 2 = A-hi-only (2 MFMA), 1 = all-hi (1 MFMA)
// BMT: M-tile (128, or 64 for fetch-bound fp32 projections -> 3 blocks/CU)
template<int ASRC, int WMODE, int PREC, int BMT>
__global__ __launch_bounds__(256) void gemm_kernel(
    const float* __restrict__ Af,
    const u16* __restrict__ A1h, const u16* __restrict__ A1l,
    const u16* __restrict__ A2h, const u16* __restrict__ A2l,
    const int* __restrict__ ridx1, const int* __restrict__ ridx2, int lda, int kpiv,
    const u16* __restrict__ Bhg, const u16* __restrict__ Blg, int ldw,
    const float* __restrict__ bias,
    u16* __restrict__ Chi, int ldc,
    const float* __restrict__ dw2, const float* __restrict__ db2,
    float* __restrict__ outv,
    int M, int K, int flags)
{
    static_assert(BMT == 128 || ASRC == 0, "BMT=64 only for fp32 projections");
    constexpr int MT = BMT / 32;                 // wave M-subtiles (4 or 2)
    constexpr int WROWS = BMT / 2;               // rows per wave (64 or 32)
    constexpr int AJ = BMT / 32;                 // A staging chunks per thread
    constexpr int A_BYTES = (ASRC == 0) ? (BMT * 128) : ((PREC == 3) ? 16384 : 8192);
    constexpr int B_BYTES = (PREC >= 2) ? 16384 : 8192;
    constexpr int BUF_BYTES = A_BYTES + B_BYTES;
    constexpr int NLOADS = (ASRC == 0) ? (AJ + 4)
                         : ((PREC == 3) ? 8 : ((PREC == 2) ? 6 : 4));
    __shared__ __align__(16) char ldsraw[2 * BUF_BYTES];
    __shared__ float red[128];

    const int tid = threadIdx.x;
    const int bm = blockIdx.x * BMT;
    const int bn = blockIdx.y * 128;
    const int l = tid & 63;
    const int w = tid >> 6;
    const int wm = w >> 1, wn = w & 1;
    const int lg = l >> 4, lr = l & 15;

    // ---- per-thread DMA sources + in-buffer dest byte offsets ----
    const float* srcAf[AJ > 0 ? AJ : 1];
    const u16 *srcA1h[2], *srcA1l[2], *srcA2h[2], *srcA2l[2];
    const u16 *srcBh[2], *srcBl[2];
    int offAf[AJ > 0 ? AJ : 1], offAh[2], offAl[2], offBh[2], offBl[2];

    if constexpr (ASRC == 0) {
        #pragma unroll
        for (int j = 0; j < AJ; ++j) {
            int g = (w * AJ + j) * 64 + l;
            int r = g >> 3, cg = g & 7;
            int rg = bm + r; if (rg > M - 1) rg = M - 1;
            long ar = ridx1 ? (long)ridx1[rg] : (long)rg;
            srcAf[j] = Af + ar * lda + (cg ^ (r & 7)) * 4;
            offAf[j] = (w * AJ + j) * 1024;          // 64 lanes * 16 B
        }
    } else {
        #pragma unroll
        for (int j = 0; j < 2; ++j) {
            int g = (w * 2 + j) * 64 + l;
            int r = g >> 2, cg = g & 3;
            int rg = bm + r; if (rg > M - 1) rg = M - 1;
            int col = (cg ^ (r & 3)) * 8;
            long a1 = ridx1 ? (long)ridx1[rg] : (long)rg;
            srcA1h[j] = A1h + a1 * lda + col;
            if constexpr (PREC == 3) srcA1l[j] = A1l + a1 * lda + col;
            if constexpr (ASRC == 2) {
                long a2 = ridx2 ? (long)ridx2[rg] : (long)rg;
                srcA2h[j] = A2h + a2 * lda + col - kpiv;
                if constexpr (PREC == 3) srcA2l[j] = A2l + a2 * lda + col - kpiv;
            }
            offAh[j] = (w * 2 + j) * 1024;
            offAl[j] = 8192 + (w * 2 + j) * 1024;
        }
    }
    #pragma unroll
    for (int j = 0; j < 2; ++j) {
        int g = (w * 2 + j) * 64 + l;
        int r = g >> 2, cg = g & 3;
        int col = (cg ^ (r & 3)) * 8;
        srcBh[j] = Bhg + (long)(bn + r) * ldw + col;
        if constexpr (PREC >= 2) srcBl[j] = Blg + (long)(bn + r) * ldw + col;
        offBh[j] = A_BYTES + (w * 2 + j) * 1024;
        offBl[j] = A_BYTES + 8192 + (w * 2 + j) * 1024;
    }

    auto ISSUE = [&](int k0, int bo) {
        char* buf = ldsraw + bo;
        if constexpr (ASRC == 0) {
            #pragma unroll
            for (int j = 0; j < AJ; ++j) gload16(srcAf[j] + k0, buf + offAf[j]);
        } else if constexpr (ASRC == 1) {
            #pragma unroll
            for (int j = 0; j < 2; ++j) {
                gload16(srcA1h[j] + k0, buf + offAh[j]);
                if constexpr (PREC == 3) gload16(srcA1l[j] + k0, buf + offAl[j]);
            }
        } else {
            bool first = k0 < kpiv;
            #pragma unroll
            for (int j = 0; j < 2; ++j) {
                gload16((first ? srcA1h[j] : srcA2h[j]) + k0, buf + offAh[j]);
                if constexpr (PREC == 3) gload16((first ? srcA1l[j] : srcA2l[j]) + k0, buf + offAl[j]);
            }
        }
        #pragma unroll
        for (int j = 0; j < 2; ++j) {
            gload16(srcBh[j] + k0, buf + offBh[j]);
            if constexpr (PREC >= 2) gload16(srcBl[j] + k0, buf + offBl[j]);
        }
    };

    f32x4 acc[MT][4];
    #pragma unroll
    for (int i = 0; i < MT; ++i)
        #pragma unroll
        for (int j = 0; j < 4; ++j) acc[i][j] = (f32x4){0.f, 0.f, 0.f, 0.f};

    bf16x8 fah[MT], fal[MT], fbh[4], fbl[4];
    float4 vaf[MT][2];

    auto READ_FRAGS = [&](int bo) {
        const char* buf = ldsraw + bo;
        const float* Af32b = (const float*)buf;
        const u16* AhB = (const u16*)buf;
        const u16* AlB = (const u16*)(buf + 8192);
        const u16* BhB = (const u16*)(buf + A_BYTES);
        const u16* BlB = (const u16*)(buf + A_BYTES + 8192);
        #pragma unroll
        for (int mt = 0; mt < MT; ++mt) {
            int r = wm * WROWS + mt * 16 + lr;
            if constexpr (ASRC == 0) {
                int cg0 = (lg * 2) ^ (r & 7);
                int cg1 = (lg * 2 + 1) ^ (r & 7);
                vaf[mt][0] = *(const float4*)&Af32b[r * 32 + cg0 * 4];
                vaf[mt][1] = *(const float4*)&Af32b[r * 32 + cg1 * 4];
            } else {
                int cg = lg ^ (r & 3);
                fah[mt] = *(const bf16x8*)&AhB[r * 32 + cg * 8];
                if constexpr (PREC == 3) fal[mt] = *(const bf16x8*)&AlB[r * 32 + cg * 8];
            }
        }
        #pragma unroll
        for (int nt = 0; nt < 4; ++nt) {
            int r = wn * 64 + nt * 16 + lr;
            int cg = lg ^ (r & 3);
            fbh[nt] = *(const bf16x8*)&BhB[r * 32 + cg * 8];
            if constexpr (PREC >= 2) fbl[nt] = *(const bf16x8*)&BlB[r * 32 + cg * 8];
        }
    };

    auto COMPUTE = [&]() {
        if constexpr (ASRC == 0) {
            #pragma unroll
            for (int mt = 0; mt < MT; ++mt) {
                float vv[8] = {vaf[mt][0].x, vaf[mt][0].y, vaf[mt][0].z, vaf[mt][0].w,
                               vaf[mt][1].x, vaf[mt][1].y, vaf[mt][1].z, vaf[mt][1].w};
                bf16x8 h8, l8;
                #pragma unroll
                for (int q = 0; q < 8; ++q) {
                    u16 hh, ll; split2(vv[q], hh, ll);
                    h8[q] = (short)hh; l8[q] = (short)ll;
                }
                fah[mt] = h8; fal[mt] = l8;
            }
        }
        #pragma unroll
        for (int mt = 0; mt < MT; ++mt)
            #pragma unroll
            for (int nt = 0; nt < 4; ++nt) {
                acc[mt][nt] = __builtin_amdgcn_mfma_f32_16x16x32_bf16(fah[mt], fbh[nt], acc[mt][nt], 0, 0, 0);
                if constexpr (PREC >= 2)
                    acc[mt][nt] = __builtin_amdgcn_mfma_f32_16x16x32_bf16(fah[mt], fbl[nt], acc[mt][nt], 0, 0, 0);
                if constexpr (PREC >= 3)
                    acc[mt][nt] = __builtin_amdgcn_mfma_f32_16x16x32_bf16(fal[mt], fbh[nt], acc[mt][nt], 0, 0, 0);
            }
    };

    // ---- counted-vmcnt 2-buffer K loop (T3+T4 minimum recipe) ----
    ISSUE(0, 0);
    if (K > 32) ISSUE(32, BUF_BYTES);
    int cur = 0;
    for (int k0 = 0; k0 < K; k0 += 32) {
        if (k0 + 32 < K) {
            if constexpr (NLOADS == 8)      asm volatile("s_waitcnt vmcnt(8)" ::: "memory");
            else if constexpr (NLOADS == 6) asm volatile("s_waitcnt vmcnt(6)" ::: "memory");
            else                            asm volatile("s_waitcnt vmcnt(4)" ::: "memory");
        } else {
            asm volatile("s_waitcnt vmcnt(0)" ::: "memory");
        }
        __builtin_amdgcn_s_barrier();
        __builtin_amdgcn_sched_barrier(0);
        int bo_cur = cur * BUF_BYTES;
        READ_FRAGS(bo_cur);
        asm volatile("s_waitcnt lgkmcnt(0)" ::: "memory");
        __builtin_amdgcn_sched_barrier(0);
        __builtin_amdgcn_s_barrier();
        if (k0 + 64 < K) ISSUE(k0 + 64, bo_cur);
        COMPUTE();
        cur ^= 1;
    }

    // ---- epilogue ----
    if constexpr (WMODE == 2) {
        if (tid < 128) red[tid] = 0.f;
        __syncthreads();
        float bv[4], dwv[4];
        #pragma unroll
        for (int nt = 0; nt < 4; ++nt) {
            int colg = wn * 64 + nt * 16 + lr;
            bv[nt] = bias[colg];
            dwv[nt] = dw2[colg];
        }
        #pragma unroll
        for (int mt = 0; mt < MT; ++mt)
            #pragma unroll
            for (int j = 0; j < 4; ++j) {
                float p = 0.f;
                #pragma unroll
                for (int nt = 0; nt < 4; ++nt)
                    p += fmaxf(acc[mt][nt][j] + bv[nt], 0.f) * dwv[nt];
                p += __shfl_xor(p, 1);
                p += __shfl_xor(p, 2);
                p += __shfl_xor(p, 4);
                p += __shfl_xor(p, 8);
                if (lr == 0) atomicAdd(&red[wm * WROWS + mt * 16 + lg * 4 + j], p);
            }
        __syncthreads();
        if (tid < BMT) {
            int row = bm + tid;
            if (row < M) outv[row] = red[tid] + db2[0];
        }
    } else {
        float bv[4];
        int col[4];
        #pragma unroll
        for (int nt = 0; nt < 4; ++nt) {
            col[nt] = bn + wn * 64 + nt * 16 + lr;
            bv[nt] = bias ? bias[col[nt]] : 0.f;
        }
        #pragma unroll
        for (int mt = 0; mt < MT; ++mt) {
            int row0 = bm + wm * WROWS + mt * 16 + lg * 4;
            #pragma unroll
            for (int j = 0; j < 4; ++j) {
                int row = row0 + j;
                if (row >= M) continue;
                size_t rbase = (size_t)row * ldc;
                #pragma unroll
                for (int nt = 0; nt < 4; ++nt) {
                    float v = acc[mt][nt][j] + bv[nt];
                    if (flags & FLAG_RELU) v = fmaxf(v, 0.f);
                    Chi[rbase + col[nt]] = f2bf(v);
                }
            }
        }
    }
}

// ---------------- CSR build (merged, sections A|B|C|D) ----------------
__global__ void count_all_kernel(const int* __restrict__ hks, const int* __restrict__ hkd,
                                 const int* __restrict__ hss, const int* __restrict__ hsd,
                                 int* __restrict__ deg)
{
    int e = blockIdx.x * blockDim.x + threadIdx.x;
    if (e < E_HK) {
        atomicAdd(deg + OFFA + hkd[e], 1);
        atomicAdd(deg + OFFC + hks[e], 1);
    } else if (e < E_HK + E_HS) {
        int i = e - E_HK;
        atomicAdd(deg + OFFB + hsd[i], 1);
        atomicAdd(deg + OFFD + hss[i], 1);
    }
}

__global__ void scan_block_kernel(const int* __restrict__ in, int* __restrict__ out,
                                  int* __restrict__ bsum, int n)
{
    __shared__ int tmp[256];
    int i = blockIdx.x * 256 + threadIdx.x;
    int v = (i < n) ? in[i] : 0;
    tmp[threadIdx.x] = v;
    __syncthreads();
    #pragma unroll
    for (int off = 1; off < 256; off <<= 1) {
        int t = (threadIdx.x >= off) ? tmp[threadIdx.x - off] : 0;
        __syncthreads();
        tmp[threadIdx.x] += t;
        __syncthreads();
    }
    if (i < n) out[i] = tmp[threadIdx.x] - v;
    if (threadIdx.x == 255 && bsum) bsum[blockIdx.x] = tmp[255];
}

__global__ void scan2_kernel(int* __restrict__ data, int n) // n <= 512, in-place exclusive
{
    __shared__ int tmp[512];
    int v = (threadIdx.x < n) ? data[threadIdx.x] : 0;
    tmp[threadIdx.x] = v;
    __syncthreads();
    #pragma unroll
    for (int off = 1; off < 512; off <<= 1) {
        int t = (threadIdx.x >= off) ? tmp[threadIdx.x - off] : 0;
        __syncthreads();
        tmp[threadIdx.x] += t;
        __syncthreads();
    }
    if (threadIdx.x < n) data[threadIdx.x] = tmp[threadIdx.x] - v;
}

__global__ void scan_add_kernel(int* __restrict__ out, const int* __restrict__ bsumex, int n)
{
    int i = blockIdx.x * 256 + threadIdx.x;
    if (i < n) out[i] += bsumex[blockIdx.x];
}

__global__ void fill_all_kernel(const int* __restrict__ hks, const int* __restrict__ hkd,
                                const int* __restrict__ hss, const int* __restrict__ hsd,
                                int* __restrict__ cur, u16* __restrict__ adj)
{
    int e = blockIdx.x * blockDim.x + threadIdx.x;
    if (e < E_HK) {
        int s = hks[e], d = hkd[e];
        int p = atomicAdd(cur + OFFA + d, 1); adj[p] = (u16)s;
        int q = atomicAdd(cur + OFFC + s, 1); adj[q] = (u16)d;
    } else if (e < E_HK + E_HS) {
        int i = e - E_HK;
        int s = hss[i], d = hsd[i];
        int p = atomicAdd(cur + OFFB + d, 1); adj[p] = (u16)s;
        int q = atomicAdd(cur + OFFD + s, 1); adj[q] = (u16)d;
    }
}

// ---------------- gather mean (hi-plane read; hi-only write; 16B/lane) ----------------
template <int D>
__global__ void gather_mean_kernel(const u16* __restrict__ Xhi,
                                   const int* __restrict__ cur, const int* __restrict__ deg,
                                   const u16* __restrict__ adj,
                                   u16* __restrict__ Ohi, int ndst)
{
    constexpr int LANES = D / 8;          // 16B per lane
    constexpr int RPB = 256 / LANES;
    int r = blockIdx.x * RPB + threadIdx.x / LANES;
    if (r >= ndst) return;
    int lane = threadIdx.x % LANES;
    int end = cur[r];
    int n = deg[r];
    int j = end - n;
    float s[8];
    #pragma unroll
    for (int q = 0; q < 8; ++q) s[q] = 0.f;
    for (; j + 1 < end; j += 2) {
        u16x8 a = *(const u16x8*)(Xhi + (size_t)adj[j] * D + lane * 8);
        u16x8 b = *(const u16x8*)(Xhi + (size_t)adj[j + 1] * D + lane * 8);
        #pragma unroll
        for (int q = 0; q < 8; ++q) s[q] += bf2f(a[q]) + bf2f(b[q]);
    }
    if (j < end) {
        u16x8 a = *(const u16x8*)(Xhi + (size_t)adj[j] * D + lane * 8);
        #pragma unroll
        for (int q = 0; q < 8; ++q) s[q] += bf2f(a[q]);
    }
    float inv = (n > 0) ? 1.0f / (float)n : 0.f;
    size_t off = (size_t)r * D + lane * 8;
    u16x8 h8;
    #pragma unroll
    for (int q = 0; q < 8; ++q) h8[q] = f2bf(s[q] * inv);
    *(u16x8*)(Ohi + off) = h8;
}

// ---------------- fused news assembly: N = [relu](N + meanC(PP) + meanD(PP2)) ----------------
template <int D, bool RELU>
__global__ void fuse_news_kernel(const u16* __restrict__ PPh, const u16* __restrict__ PP2h,
                                 const int* __restrict__ curC, const int* __restrict__ degC,
                                 const int* __restrict__ curD, const int* __restrict__ degD,
                                 const u16* __restrict__ adj,
                                 u16* __restrict__ Nh, int ndst)
{
    constexpr int LANES = D / 8;          // 16B per lane
    constexpr int RPB = 256 / LANES;
    int r = blockIdx.x * RPB + threadIdx.x / LANES;
    if (r >= ndst) return;
    int lane = threadIdx.x % LANES;
    float s[8];
    #pragma unroll
    for (int q = 0; q < 8; ++q) s[q] = 0.f;
    {
        int end = curC[r], n = degC[r];
        float a[8];
        #pragma unroll
        for (int q = 0; q < 8; ++q) a[q] = 0.f;
        for (int j = end - n; j < end; ++j) {
            u16x8 v = *(const u16x8*)(PPh + (size_t)adj[j] * D + lane * 8);
            #pragma unroll
            for (int q = 0; q < 8; ++q) a[q] += bf2f(v[q]);
        }
        float inv = (n > 0) ? 1.0f / (float)n : 0.f;
        #pragma unroll
        for (int q = 0; q < 8; ++q) s[q] += a[q] * inv;
    }
    {
        int end = curD[r], n = degD[r];
        float a[8];
        #pragma unroll
        for (int q = 0; q < 8; ++q) a[q] = 0.f;
        for (int j = end - n; j < end; ++j) {
            u16x8 v = *(const u16x8*)(PP2h + (size_t)adj[j] * D + lane * 8);
            #pragma unroll
            for (int q = 0; q < 8; ++q) a[q] += bf2f(v[q]);
        }
        float inv = (n > 0) ? 1.0f / (float)n : 0.f;
        #pragma unroll
        for (int q = 0; q < 8; ++q) s[q] += a[q] * inv;
    }
    size_t off = (size_t)r * D + lane * 8;
    u16x8 h = *(const u16x8*)(Nh + off);
    #pragma unroll
    for (int q = 0; q < 8; ++q) {
        float v = s[q] + bf2f(h[q]);
        if (RELU) v = fmaxf(v, 0.f);
        s[q] = v;
    }
    u16x8 oh;
    #pragma unroll
    for (int q = 0; q < 8; ++q) oh[q] = f2bf(s[q]);
    *(u16x8*)(Nh + off) = oh;
}

// ---------------- batched weight split/convert ----------------
#define MAXJOBS 20
struct SplitJobs {
    const float* a[MAXJOBS];
    const float* b[MAXJOBS];     // optional second operand (summed)
    u16* hi[MAXJOBS];
    u16* lo[MAXJOBS];
    int n[MAXJOBS];
    int ncols[MAXJOBS];          // source row width
    int dstride[MAXJOBS];        // dest row stride
    int boff[MAXJOBS + 1];
    int njobs;
};

__global__ void split_all_kernel(SplitJobs J)
{
    int bid = blockIdx.x;
    int j = 0;
    while (j + 1 < J.njobs && bid >= J.boff[j + 1]) ++j;
    int i = (bid - J.boff[j]) * 1024 + threadIdx.x * 4;
    if (i >= J.n[j]) return;
    float4 v = *(const float4*)(J.a[j] + i);
    if (J.b[j]) {
        float4 w = *(const float4*)(J.b[j] + i);
        v.x += w.x; v.y += w.y; v.z += w.z; v.w += w.w;
    }
    int row = i / J.ncols[j], col = i - row * J.ncols[j];
    size_t d = (size_t)row * J.dstride[j] + col;
    ushort4 h, l;
    split2(v.x, h.x, l.x); split2(v.y, h.y, l.y); split2(v.z, h.z, l.z); split2(v.w, h.w, l.w);
    *(ushort4*)(J.hi[j] + d) = h;
    *(ushort4*)(J.lo[j] + d) = l;
}

__global__ void bias_sum_kernel(const float* __restrict__ b1, const float* __restrict__ b2,
                                float* __restrict__ BS1, float* __restrict__ BS2)
{
    int i = blockIdx.x * 256 + threadIdx.x;
    if (i < 256) BS1[i] = b1[256 + i] + b1[768 + i];
    else if (i < 384) { int j = i - 256; BS2[j] = b2[128 + j] + b2[384 + j]; }
}

// ---------------- launch ----------------
extern "C" void kernel_launch(void* const* d_in, const int* in_sizes, int n_in,
                              void* d_out, int out_size, void* d_ws, size_t ws_size,
                              hipStream_t stream)
{
    const float* x_news = (const float*)d_in[0];
    const float* x_kw   = (const float*)d_in[1];
    const float* x_st   = (const float*)d_in[2];
    const float* Wn = (const float*)d_in[3];  const float* bn = (const float*)d_in[4];
    const float* Wk = (const float*)d_in[5];  const float* bk = (const float*)d_in[6];
    const float* Wst = (const float*)d_in[7]; const float* bs = (const float*)d_in[8];
    const float* W1l = (const float*)d_in[9];  const float* b1 = (const float*)d_in[10];
    const float* W1r = (const float*)d_in[11];
    const float* W2l = (const float*)d_in[12]; const float* b2 = (const float*)d_in[13];
    const float* W2r = (const float*)d_in[14];
    const float* DW1 = (const float*)d_in[15]; const float* Db1 = (const float*)d_in[16];
    const float* DW2 = (const float*)d_in[17]; const float* Db2 = (const float*)d_in[18];
    const int* e_hk_src = (const int*)d_in[19];
    const int* e_hk_dst = (const int*)d_in[20];
    const int* e_hs_src = (const int*)d_in[21];
    const int* e_hs_dst = (const int*)d_in[22];
    const int* l_hk_src = (const int*)d_in[23];
    const int* l_hk_dst = (const int*)d_in[24];
    const int* l_hs_src = (const int*)d_in[25];
    const int* l_hs_dst = (const int*)d_in[26];
    float* out = (float*)d_out;

    // ---- workspace layout (bytes, 16B aligned) ----
    char* base = (char*)d_ws;
    auto alloc = [&](size_t bytes) -> char* {
        char* p = base;
        base += (bytes + 15) & ~(size_t)15;
        return p;
    };
    auto aplane = [&](size_t elems) -> u16* { return (u16*)alloc(elems * 2); };

    u16* HNh = aplane((size_t)N_NEWS * HID);
    u16* HKh = aplane((size_t)N_KW * HID);
    u16* HSh = aplane((size_t)N_ST * HID);
    u16* K1h = aplane((size_t)N_KW * HID);
    u16* S1h = aplane((size_t)N_ST * HID);
    u16* PAh = aplane((size_t)(N_KW + N_ST) * HID);   // 12000 rows (kw | st sections)
    u16* PAl = aplane((size_t)(N_KW + N_ST) * HID);   // PP2 buffer (st projections)
    u16* N1h = aplane((size_t)N_NEWS * HID);
    // weight planes
    u16* WnH = aplane(196608);  u16* WnL = aplane(196608);
    u16* WkH = aplane(32768);   u16* WkL = aplane(32768);
    u16* WsH = aplane(16384);   u16* WsL = aplane(16384);
    u16* CW1KH = aplane(131072); u16* CW1KL = aplane(131072);  // [256][512] W1l0|W1r0
    u16* CW1SH = aplane(131072); u16* CW1SL = aplane(131072);  // [256][512] W1l2|W1r2
    u16* W1l1H = aplane(65536);  u16* W1l1L = aplane(65536);
    u16* W1l3H = aplane(65536);  u16* W1l3L = aplane(65536);
    u16* SW1H = aplane(65536);   u16* SW1L = aplane(65536);    // W1r1+W1r3
    u16* CW2KH = aplane(65536);  u16* CW2KL = aplane(65536);   // [128][512] W2l0|W2r0
    u16* CW2SH = aplane(65536);  u16* CW2SL = aplane(65536);   // [128][512] W2l2|W2r2
    u16* W2l1H = aplane(32768);  u16* W2l1L = aplane(32768);
    u16* W2l3H = aplane(32768);  u16* W2l3L = aplane(32768);
    u16* SW2H = aplane(32768);   u16* SW2L = aplane(32768);    // W2r1+W2r3
    u16* DW1H = aplane(65536);   u16* DW1L = aplane(65536);
    float* BS1 = (float*)alloc(256 * 4);
    float* BS2 = (float*)alloc(128 * 4);
    // int pools
    int* deg = (int*)alloc((size_t)NTOT * 4);
    int* cur = (int*)alloc((size_t)NTOT * 4);
    u16* adj = (u16*)alloc((size_t)2 * (E_HK + E_HS) * 2);
    int* bsum = (int*)alloc(512 * 4);

    // overlays: layer-2 outputs reuse the HN region (dead after layer 1)
    u16* K2h = HNh;
    u16* N2h = K2h + (size_t)N_KW * OUTD;
    u16* S2h = N2h + (size_t)N_NEWS * OUTD;

    // ---- CSR build ----
    hipMemsetAsync(deg, 0, (size_t)NTOT * sizeof(int), stream);
    int etot = E_HK + E_HS;
    count_all_kernel<<<(etot + 255) / 256, 256, 0, stream>>>(e_hk_src, e_hk_dst, e_hs_src, e_hs_dst, deg);
    int nb = (NTOT + 255) / 256; // 438
    scan_block_kernel<<<nb, 256, 0, stream>>>(deg, cur, bsum, NTOT);
    scan2_kernel<<<1, 512, 0, stream>>>(bsum, nb);
    scan_add_kernel<<<nb, 256, 0, stream>>>(cur, bsum, NTOT);
    fill_all_kernel<<<(etot + 255) / 256, 256, 0, stream>>>(e_hk_src, e_hk_dst, e_hs_src, e_hs_dst, cur, adj);

    // ---- batched weight conversion ----
    {
        SplitJobs J{};
        int nj = 0, blocks = 0;
        auto job = [&](const float* a, const float* b, u16* hi, u16* lo, int n, int ncols, int dstride) {
            J.a[nj] = a; J.b[nj] = b; J.hi[nj] = hi; J.lo[nj] = lo;
            J.n[nj] = n; J.ncols[nj] = ncols; J.dstride[nj] = dstride;
            J.boff[nj] = blocks;
            blocks += (n / 4 + 255) / 256;
            ++nj;
        };
        job(Wn, nullptr, WnH, WnL, 196608, 196608, 196608);
        job(Wk, nullptr, WkH, WkL, 32768, 32768, 32768);
        job(Wst, nullptr, WsH, WsL, 16384, 16384, 16384);
        job(W1l + 0 * 65536, nullptr, CW1KH, CW1KL, 65536, 256, 512);
        job(W1r + 0 * 65536, nullptr, CW1KH + 256, CW1KL + 256, 65536, 256, 512);
        job(W1l + 2 * 65536, nullptr, CW1SH, CW1SL, 65536, 256, 512);
        job(W1r + 2 * 65536, nullptr, CW1SH + 256, CW1SL + 256, 65536, 256, 512);
        job(W1l + 1 * 65536, nullptr, W1l1H, W1l1L, 65536, 65536, 65536);
        job(W1l + 3 * 65536, nullptr, W1l3H, W1l3L, 65536, 65536, 65536);
        job(W1r + 1 * 65536, W1r + 3 * 65536, SW1H, SW1L, 65536, 65536, 65536);
        job(W2l + 0 * 32768, nullptr, CW2KH, CW2KL, 32768, 256, 512);
        job(W2r + 0 * 32768, nullptr, CW2KH + 256, CW2KL + 256, 32768, 256, 512);
        job(W2l + 2 * 32768, nullptr, CW2SH, CW2SL, 32768, 256, 512);
        job(W2r + 2 * 32768, nullptr, CW2SH + 256, CW2SL + 256, 32768, 256, 512);
        job(W2l + 1 * 32768, nullptr, W2l1H, W2l1L, 32768, 32768, 32768);
        job(W2l + 3 * 32768, nullptr, W2l3H, W2l3L, 32768, 32768, 32768);
        job(W2r + 1 * 32768, W2r + 3 * 32768, SW2H, SW2L, 32768, 32768, 32768);
        job(DW1, nullptr, DW1H, DW1L, 65536, 65536, 65536);
        J.boff[nj] = blocks;
        J.njobs = nj;
        split_all_kernel<<<blocks, 256, 0, stream>>>(J);
    }
    bias_sum_kernel<<<2, 256, 0, stream>>>(b1, b2, BS1, BS2);

    // ---- GEMM wrappers ----
    // fp32-A projection, full split (3 MFMA), hi-only C, BM=64 (fetch-bound)
    auto gemmF = [&](const float* A, int lda, const u16* Bh, const u16* Bl, int ldw,
                     const float* bias, u16* Ch, int ldc,
                     int M, int N, int K, int flags) {
        dim3 g((M + 63) / 64, N / 128);
        gemm_kernel<0, 1, 3, 64><<<g, 256, 0, stream>>>(
            A, nullptr, nullptr, nullptr, nullptr, nullptr, nullptr, lda, 0,
            Bh, Bl, ldw, bias, Ch, ldc, nullptr, nullptr, nullptr, M, K, flags);
    };
    // PREC=2 plane GEMM (A hi-only, B full, 2 MFMA), hi-only C
    auto gemmP2 = [&](const u16* Ahp, int lda, const u16* Bh, const u16* Bl, int ldw,
                      const float* bias, u16* Ch, int ldc,
                      int M, int N, int K, int flags) {
        dim3 g((M + 127) / 128, N / 128);
        gemm_kernel<1, 1, 2, 128><<<g, 256, 0, stream>>>(
            nullptr, Ahp, nullptr, nullptr, nullptr, nullptr, nullptr, lda, 0,
            Bh, Bl, ldw, bias, Ch, ldc, nullptr, nullptr, nullptr, M, K, flags);
    };
    // PREC=2 dual-table GEMM (A hi-only, B full), hi-only C
    auto gemm22 = [&](const u16* A1hp, const u16* A2hp, int lda, int kpiv,
                      const u16* Bh, const u16* Bl, int ldw,
                      const float* bias, u16* Ch, int ldc,
                      int M, int N, int K, int flags) {
        dim3 g((M + 127) / 128, N / 128);
        gemm_kernel<2, 1, 2, 128><<<g, 256, 0, stream>>>(
            nullptr, A1hp, nullptr, A2hp, nullptr, nullptr, nullptr, lda, kpiv,
            Bh, Bl, ldw, bias, Ch, ldc, nullptr, nullptr, nullptr, M, K, flags);
    };
    // PREC=1 plane GEMM (1 MFMA), hi-only C
    auto gemmLP = [&](const u16* Ahp, int lda, const u16* Bh, int ldw,
                      const float* bias, u16* Ch, int ldc, int M, int N, int K, int flags) {
        dim3 g((M + 127) / 128, N / 128);
        gemm_kernel<1, 1, 1, 128><<<g, 256, 0, stream>>>(
            nullptr, Ahp, nullptr, nullptr, nullptr, nullptr, nullptr, lda, 0,
            Bh, nullptr, ldw, bias, Ch, ldc, nullptr, nullptr, nullptr, M, K, flags);
    };
    // PREC=1 dual-table GEMM, hi-only C
    auto gemmL2 = [&](const u16* A1hp, const u16* A2hp, int lda, int kpiv,
                      const u16* Bh, int ldw, const float* bias, u16* Ch, int ldc,
                      int M, int N, int K, int flags) {
        dim3 g((M + 127) / 128, N / 128);
        gemm_kernel<2, 1, 1, 128><<<g, 256, 0, stream>>>(
            nullptr, A1hp, nullptr, A2hp, nullptr, nullptr, nullptr, lda, kpiv,
            Bh, nullptr, ldw, bias, Ch, ldc, nullptr, nullptr, nullptr, M, K, flags);
    };
    // PREC=1 fused decoder
    auto gemmD = [&](const u16* A1hp, const u16* A2hp,
                     const int* r1, const int* r2, const u16* Bh,
                     const float* bias, const float* dw2, const float* db2, float* ov) {
        dim3 g((E_LBL + 127) / 128, 1);
        gemm_kernel<2, 2, 1, 128><<<g, 256, 0, stream>>>(
            nullptr, A1hp, nullptr, A2hp, nullptr, r1, r2, 128, 128,
            Bh, nullptr, 256, bias, nullptr, 0, dw2, db2, ov, E_LBL, 256, 0);
    };

    // ---- input projections (fp32 A, full split, hi-only outputs, BM=64) ----
    gemmF(x_news, F_NEWS, WnH, WnL, F_NEWS, bn, HNh, HID, N_NEWS, HID, F_NEWS, FLAG_RELU);
    gemmF(x_kw,   F_KW,   WkH, WkL, F_KW,   bk, HKh, HID, N_KW,   HID, F_KW,   FLAG_RELU);
    gemmF(x_st,   F_ST,   WsH, WsL, F_ST,   bs, HSh, HID, N_ST,   HID, F_ST,   FLAG_RELU);

    // ---- layer 1 (PREC=2: bf16 activations x full-split weights) ----
    gather_mean_kernel<256><<<(N_KW + N_ST + 7) / 8, 256, 0, stream>>>(
        HNh, cur + OFFA, deg + OFFA, adj, PAh, N_KW + N_ST);
    gemm22(PAh, HKh, HID, 256, CW1KH, CW1KL, 512, b1, K1h, HID, N_KW, HID, 512, FLAG_RELU);
    gemm22(PAh + (size_t)N_KW * HID, HSh, HID, 256,
           CW1SH, CW1SL, 512, b1 + 2 * 256, S1h, HID, N_ST, HID, 512, FLAG_RELU);
    gemmLP(HKh, HID, W1l1H, HID, nullptr, PAh, HID, N_KW, HID, HID, 0);   // PP
    gemmLP(HSh, HID, W1l3H, HID, nullptr, PAl, HID, N_ST, HID, HID, 0);   // PP2
    gemmP2(HNh, HID, SW1H, SW1L, HID, BS1, N1h, HID, N_NEWS, HID, HID, 0);
    fuse_news_kernel<256, true><<<(N_NEWS + 7) / 8, 256, 0, stream>>>(
        PAh, PAl, cur + OFFC, deg + OFFC, cur + OFFD, deg + OFFD, adj, N1h, N_NEWS);

    // ---- layer 2 (PREC=1: hi-only, 1 MFMA) ----
    gather_mean_kernel<256><<<(N_KW + N_ST + 7) / 8, 256, 0, stream>>>(
        N1h, cur + OFFA, deg + OFFA, adj, PAh, N_KW + N_ST);
    gemmL2(PAh, K1h, HID, 256, CW2KH, 512, b2, K2h, OUTD, N_KW, OUTD, 512, 0);
    gemmL2(PAh + (size_t)N_KW * HID, S1h, HID, 256, CW2SH, 512, b2 + 2 * 128, S2h, OUTD, N_ST, OUTD, 512, 0);
    gemmLP(K1h, HID, W2l1H, HID, nullptr, PAh, OUTD, N_KW, OUTD, HID, 0);  // PP (n2)
    gemmLP(S1h, HID, W2l3H, HID, nullptr, PAl, OUTD, N_ST, OUTD, HID, 0);  // PP2 (n2)
    gemmLP(N1h, HID, SW2H, HID, BS2, N2h, OUTD, N_NEWS, OUTD, HID, 0);
    fuse_news_kernel<128, false><<<(N_NEWS + 15) / 16, 256, 0, stream>>>(
        PAh, PAl, cur + OFFC, deg + OFFC, cur + OFFD, deg + OFFD, adj, N2h, N_NEWS);

    // ---- fused decoders (PREC=1) ----
    gemmD(N2h, K2h, l_hk_src, l_hk_dst, DW1H, Db1, DW2, Db2, out);
    gemmD(N2h, S2h, l_hs_src, l_hs_dst, DW1H + 32768, Db1 + 128, DW2 + 128, Db2 + 1, out + E_LBL);
}

// Round 18
// 695.037 us; speedup vs baseline: 1.0070x; 1.0070x over previous
//
#include <hip/hip_runtime.h>
#include <hip/hip_bf16.h>

// ---------------- problem constants ----------------
constexpr int N_NEWS = 50000, N_KW = 10000, N_ST = 2000;
constexpr int F_NEWS = 768, F_KW = 128, F_ST = 64;
constexpr int HID = 256, OUTD = 128;
constexpr int E_HK = 500000, E_HS = 250000, E_LBL = 150000;

// CSR section offsets in the concatenated degree/cursor pools
constexpr int OFFA = 0;                    // e_hk keyed by dst (kw)
constexpr int OFFB = N_KW;                 // e_hs keyed by dst (st)
constexpr int OFFC = N_KW + N_ST;          // e_hk keyed by src (news)
constexpr int OFFD = OFFC + N_NEWS;        // e_hs keyed by src (news)
constexpr int NTOT = OFFD + N_NEWS;        // 112000

enum { FLAG_ACC = 1, FLAG_RELU = 2 };

typedef unsigned short u16;
typedef __attribute__((ext_vector_type(8))) short bf16x8;
typedef __attribute__((ext_vector_type(8))) unsigned short u16x8;
typedef __attribute__((ext_vector_type(4))) float f32x4;

__device__ __forceinline__ u16 f2bf(float x) {
    return __builtin_bit_cast(u16, __float2bfloat16(x));
}
__device__ __forceinline__ float bf2f(u16 h) {
    unsigned u = ((unsigned)h) << 16;
    return __builtin_bit_cast(float, u);
}
__device__ __forceinline__ void split2(float x, u16& h, u16& l) {
    h = f2bf(x);
    l = f2bf(x - bf2f(h));
}

// async global->LDS DMA, 16B per lane; LDS dest = wave-uniform base + lane*16
__device__ __forceinline__ void gload16(const void* g, void* s) {
    __builtin_amdgcn_global_load_lds(
        (const __attribute__((address_space(1))) void*)g,
        (__attribute__((address_space(3))) void*)s, 16, 0, 0);
}

// ---------------- split-bf16 MFMA GEMM, dbuf LDS + COUNTED-vmcnt pipeline (T3+T4) ------
// ASRC: 0 = fp32 A (DMA fp32, split in regs), 1 = plane A, 2 = dual-table plane A
// WMODE: 1 = hi-only C write, 2 = fused decoder reduce -> outv
// PREC: 3 = full split (3 MFMA, A hi+lo, B hi+lo)
//       2 = A-hi-only (2 MFMA: ah*bh + ah*bl; exact for bf16 A)
//       1 = all-hi (1 MFMA)
template<int ASRC, int WMODE, int PREC>
__global__ __launch_bounds__(256) void gemm_kernel(
    const float* __restrict__ Af,
    const u16* __restrict__ A1h, const u16* __restrict__ A1l,
    const u16* __restrict__ A2h, const u16* __restrict__ A2l,
    const int* __restrict__ ridx1, const int* __restrict__ ridx2, int lda, int kpiv,
    const u16* __restrict__ Bhg, const u16* __restrict__ Blg, int ldw,
    const float* __restrict__ bias,
    u16* __restrict__ Chi, int ldc,
    const float* __restrict__ dw2, const float* __restrict__ db2,
    float* __restrict__ outv,
    int M, int K, int flags)
{
    constexpr int A_BYTES = (ASRC == 0) ? 16384 : ((PREC == 3) ? 16384 : 8192);
    constexpr int B_BYTES = (PREC >= 2) ? 16384 : 8192;
    constexpr int BUF_BYTES = A_BYTES + B_BYTES;
    constexpr int NLOADS = (ASRC == 0) ? 8 : ((PREC == 3) ? 8 : ((PREC == 2) ? 6 : 4));
    __shared__ __align__(16) char ldsraw[2 * BUF_BYTES];
    __shared__ float red[128];

    const int tid = threadIdx.x;
    const int bm = blockIdx.x * 128;
    const int bn = blockIdx.y * 128;
    const int l = tid & 63;
    const int w = tid >> 6;
    const int wm = w >> 1, wn = w & 1;
    const int lg = l >> 4, lr = l & 15;

    // ---- per-thread DMA sources + in-buffer dest byte offsets ----
    const float* srcAf[4];
    const u16 *srcA1h[2], *srcA1l[2], *srcA2h[2], *srcA2l[2];
    const u16 *srcBh[2], *srcBl[2];
    int offAf[4], offAh[2], offAl[2], offBh[2], offBl[2];

    if constexpr (ASRC == 0) {
        #pragma unroll
        for (int j = 0; j < 4; ++j) {
            int g = (w * 4 + j) * 64 + l;
            int r = g >> 3, cg = g & 7;
            int rg = bm + r; if (rg > M - 1) rg = M - 1;
            long ar = ridx1 ? (long)ridx1[rg] : (long)rg;
            srcAf[j] = Af + ar * lda + (cg ^ (r & 7)) * 4;
            offAf[j] = (w * 4 + j) * 1024;           // 64 lanes * 16 B
        }
    } else {
        #pragma unroll
        for (int j = 0; j < 2; ++j) {
            int g = (w * 2 + j) * 64 + l;
            int r = g >> 2, cg = g & 3;
            int rg = bm + r; if (rg > M - 1) rg = M - 1;
            int col = (cg ^ (r & 3)) * 8;
            long a1 = ridx1 ? (long)ridx1[rg] : (long)rg;
            srcA1h[j] = A1h + a1 * lda + col;
            if constexpr (PREC == 3) srcA1l[j] = A1l + a1 * lda + col;
            if constexpr (ASRC == 2) {
                long a2 = ridx2 ? (long)ridx2[rg] : (long)rg;
                srcA2h[j] = A2h + a2 * lda + col - kpiv;
                if constexpr (PREC == 3) srcA2l[j] = A2l + a2 * lda + col - kpiv;
            }
            offAh[j] = (w * 2 + j) * 1024;
            offAl[j] = 8192 + (w * 2 + j) * 1024;
        }
    }
    #pragma unroll
    for (int j = 0; j < 2; ++j) {
        int g = (w * 2 + j) * 64 + l;
        int r = g >> 2, cg = g & 3;
        int col = (cg ^ (r & 3)) * 8;
        srcBh[j] = Bhg + (long)(bn + r) * ldw + col;
        if constexpr (PREC >= 2) srcBl[j] = Blg + (long)(bn + r) * ldw + col;
        offBh[j] = A_BYTES + (w * 2 + j) * 1024;
        offBl[j] = A_BYTES + 8192 + (w * 2 + j) * 1024;
    }

    auto ISSUE = [&](int k0, int bo) {
        char* buf = ldsraw + bo;
        if constexpr (ASRC == 0) {
            #pragma unroll
            for (int j = 0; j < 4; ++j) gload16(srcAf[j] + k0, buf + offAf[j]);
        } else if constexpr (ASRC == 1) {
            #pragma unroll
            for (int j = 0; j < 2; ++j) {
                gload16(srcA1h[j] + k0, buf + offAh[j]);
                if constexpr (PREC == 3) gload16(srcA1l[j] + k0, buf + offAl[j]);
            }
        } else {
            bool first = k0 < kpiv;
            #pragma unroll
            for (int j = 0; j < 2; ++j) {
                gload16((first ? srcA1h[j] : srcA2h[j]) + k0, buf + offAh[j]);
                if constexpr (PREC == 3) gload16((first ? srcA1l[j] : srcA2l[j]) + k0, buf + offAl[j]);
            }
        }
        #pragma unroll
        for (int j = 0; j < 2; ++j) {
            gload16(srcBh[j] + k0, buf + offBh[j]);
            if constexpr (PREC >= 2) gload16(srcBl[j] + k0, buf + offBl[j]);
        }
    };

    f32x4 acc[4][4];
    #pragma unroll
    for (int i = 0; i < 4; ++i)
        #pragma unroll
        for (int j = 0; j < 4; ++j) acc[i][j] = (f32x4){0.f, 0.f, 0.f, 0.f};

    bf16x8 fah[4], fal[4], fbh[4], fbl[4];
    float4 vaf[4][2];

    auto READ_FRAGS = [&](int bo) {
        const char* buf = ldsraw + bo;
        const float* Af32b = (const float*)buf;
        const u16* AhB = (const u16*)buf;
        const u16* AlB = (const u16*)(buf + 8192);
        const u16* BhB = (const u16*)(buf + A_BYTES);
        const u16* BlB = (const u16*)(buf + A_BYTES + 8192);
        #pragma unroll
        for (int mt = 0; mt < 4; ++mt) {
            int r = wm * 64 + mt * 16 + lr;
            if constexpr (ASRC == 0) {
                int cg0 = (lg * 2) ^ (r & 7);
                int cg1 = (lg * 2 + 1) ^ (r & 7);
                vaf[mt][0] = *(const float4*)&Af32b[r * 32 + cg0 * 4];
                vaf[mt][1] = *(const float4*)&Af32b[r * 32 + cg1 * 4];
            } else {
                int cg = lg ^ (r & 3);
                fah[mt] = *(const bf16x8*)&AhB[r * 32 + cg * 8];
                if constexpr (PREC == 3) fal[mt] = *(const bf16x8*)&AlB[r * 32 + cg * 8];
            }
        }
        #pragma unroll
        for (int nt = 0; nt < 4; ++nt) {
            int r = wn * 64 + nt * 16 + lr;
            int cg = lg ^ (r & 3);
            fbh[nt] = *(const bf16x8*)&BhB[r * 32 + cg * 8];
            if constexpr (PREC >= 2) fbl[nt] = *(const bf16x8*)&BlB[r * 32 + cg * 8];
        }
    };

    auto COMPUTE = [&]() {
        if constexpr (ASRC == 0) {
            #pragma unroll
            for (int mt = 0; mt < 4; ++mt) {
                float vv[8] = {vaf[mt][0].x, vaf[mt][0].y, vaf[mt][0].z, vaf[mt][0].w,
                               vaf[mt][1].x, vaf[mt][1].y, vaf[mt][1].z, vaf[mt][1].w};
                bf16x8 h8, l8;
                #pragma unroll
                for (int q = 0; q < 8; ++q) {
                    u16 hh, ll; split2(vv[q], hh, ll);
                    h8[q] = (short)hh; l8[q] = (short)ll;
                }
                fah[mt] = h8; fal[mt] = l8;
            }
        }
        #pragma unroll
        for (int mt = 0; mt < 4; ++mt)
            #pragma unroll
            for (int nt = 0; nt < 4; ++nt) {
                acc[mt][nt] = __builtin_amdgcn_mfma_f32_16x16x32_bf16(fah[mt], fbh[nt], acc[mt][nt], 0, 0, 0);
                if constexpr (PREC >= 2)
                    acc[mt][nt] = __builtin_amdgcn_mfma_f32_16x16x32_bf16(fah[mt], fbl[nt], acc[mt][nt], 0, 0, 0);
                if constexpr (PREC >= 3)
                    acc[mt][nt] = __builtin_amdgcn_mfma_f32_16x16x32_bf16(fal[mt], fbh[nt], acc[mt][nt], 0, 0, 0);
            }
    };

    // ---- counted-vmcnt 2-buffer K loop (T3+T4 minimum recipe) ----
    ISSUE(0, 0);
    if (K > 32) ISSUE(32, BUF_BYTES);
    int cur = 0;
    for (int k0 = 0; k0 < K; k0 += 32) {
        if (k0 + 32 < K) {
            if constexpr (NLOADS == 8)      asm volatile("s_waitcnt vmcnt(8)" ::: "memory");
            else if constexpr (NLOADS == 6) asm volatile("s_waitcnt vmcnt(6)" ::: "memory");
            else                            asm volatile("s_waitcnt vmcnt(4)" ::: "memory");
        } else {
            asm volatile("s_waitcnt vmcnt(0)" ::: "memory");
        }
        __builtin_amdgcn_s_barrier();
        __builtin_amdgcn_sched_barrier(0);
        int bo_cur = cur * BUF_BYTES;
        READ_FRAGS(bo_cur);
        asm volatile("s_waitcnt lgkmcnt(0)" ::: "memory");
        __builtin_amdgcn_sched_barrier(0);
        __builtin_amdgcn_s_barrier();
        if (k0 + 64 < K) ISSUE(k0 + 64, bo_cur);
        COMPUTE();
        cur ^= 1;
    }

    // ---- epilogue ----
    if constexpr (WMODE == 2) {
        if (tid < 128) red[tid] = 0.f;
        __syncthreads();
        float bv[4], dwv[4];
        #pragma unroll
        for (int nt = 0; nt < 4; ++nt) {
            int colg = wn * 64 + nt * 16 + lr;
            bv[nt] = bias[colg];
            dwv[nt] = dw2[colg];
        }
        #pragma unroll
        for (int mt = 0; mt < 4; ++mt)
            #pragma unroll
            for (int j = 0; j < 4; ++j) {
                float p = 0.f;
                #pragma unroll
                for (int nt = 0; nt < 4; ++nt)
                    p += fmaxf(acc[mt][nt][j] + bv[nt], 0.f) * dwv[nt];
                p += __shfl_xor(p, 1);
                p += __shfl_xor(p, 2);
                p += __shfl_xor(p, 4);
                p += __shfl_xor(p, 8);
                if (lr == 0) atomicAdd(&red[wm * 64 + mt * 16 + lg * 4 + j], p);
            }
        __syncthreads();
        if (tid < 128) {
            int row = bm + tid;
            if (row < M) outv[row] = red[tid] + db2[0];
        }
    } else {
        float bv[4];
        int col[4];
        #pragma unroll
        for (int nt = 0; nt < 4; ++nt) {
            col[nt] = bn + wn * 64 + nt * 16 + lr;
            bv[nt] = bias ? bias[col[nt]] : 0.f;
        }
        #pragma unroll
        for (int mt = 0; mt < 4; ++mt) {
            int row0 = bm + wm * 64 + mt * 16 + lg * 4;
            #pragma unroll
            for (int j = 0; j < 4; ++j) {
                int row = row0 + j;
                if (row >= M) continue;
                size_t rbase = (size_t)row * ldc;
                #pragma unroll
                for (int nt = 0; nt < 4; ++nt) {
                    float v = acc[mt][nt][j] + bv[nt];
                    if (flags & FLAG_RELU) v = fmaxf(v, 0.f);
                    Chi[rbase + col[nt]] = f2bf(v);
                }
            }
        }
    }
}

// ---------------- CSR build (merged, sections A|B|C|D) ----------------
__global__ void count_all_kernel(const int* __restrict__ hks, const int* __restrict__ hkd,
                                 const int* __restrict__ hss, const int* __restrict__ hsd,
                                 int* __restrict__ deg)
{
    int e = blockIdx.x * blockDim.x + threadIdx.x;
    if (e < E_HK) {
        atomicAdd(deg + OFFA + hkd[e], 1);
        atomicAdd(deg + OFFC + hks[e], 1);
    } else if (e < E_HK + E_HS) {
        int i = e - E_HK;
        atomicAdd(deg + OFFB + hsd[i], 1);
        atomicAdd(deg + OFFD + hss[i], 1);
    }
}

__global__ void scan_block_kernel(const int* __restrict__ in, int* __restrict__ out,
                                  int* __restrict__ bsum, int n)
{
    __shared__ int tmp[256];
    int i = blockIdx.x * 256 + threadIdx.x;
    int v = (i < n) ? in[i] : 0;
    tmp[threadIdx.x] = v;
    __syncthreads();
    #pragma unroll
    for (int off = 1; off < 256; off <<= 1) {
        int t = (threadIdx.x >= off) ? tmp[threadIdx.x - off] : 0;
        __syncthreads();
        tmp[threadIdx.x] += t;
        __syncthreads();
    }
    if (i < n) out[i] = tmp[threadIdx.x] - v;
    if (threadIdx.x == 255 && bsum) bsum[blockIdx.x] = tmp[255];
}

__global__ void scan2_kernel(int* __restrict__ data, int n) // n <= 512, in-place exclusive
{
    __shared__ int tmp[512];
    int v = (threadIdx.x < n) ? data[threadIdx.x] : 0;
    tmp[threadIdx.x] = v;
    __syncthreads();
    #pragma unroll
    for (int off = 1; off < 512; off <<= 1) {
        int t = (threadIdx.x >= off) ? tmp[threadIdx.x - off] : 0;
        __syncthreads();
        tmp[threadIdx.x] += t;
        __syncthreads();
    }
    if (threadIdx.x < n) data[threadIdx.x] = tmp[threadIdx.x] - v;
}

__global__ void scan_add_kernel(int* __restrict__ out, const int* __restrict__ bsumex, int n)
{
    int i = blockIdx.x * 256 + threadIdx.x;
    if (i < n) out[i] += bsumex[blockIdx.x];
}

__global__ void fill_all_kernel(const int* __restrict__ hks, const int* __restrict__ hkd,
                                const int* __restrict__ hss, const int* __restrict__ hsd,
                                int* __restrict__ cur, u16* __restrict__ adj)
{
    int e = blockIdx.x * blockDim.x + threadIdx.x;
    if (e < E_HK) {
        int s = hks[e], d = hkd[e];
        int p = atomicAdd(cur + OFFA + d, 1); adj[p] = (u16)s;
        int q = atomicAdd(cur + OFFC + s, 1); adj[q] = (u16)d;
    } else if (e < E_HK + E_HS) {
        int i = e - E_HK;
        int s = hss[i], d = hsd[i];
        int p = atomicAdd(cur + OFFB + d, 1); adj[p] = (u16)s;
        int q = atomicAdd(cur + OFFD + s, 1); adj[q] = (u16)d;
    }
}

// ---------------- gather mean (hi-plane read; hi-only write; 16B/lane) ----------------
template <int D>
__global__ void gather_mean_kernel(const u16* __restrict__ Xhi,
                                   const int* __restrict__ cur, const int* __restrict__ deg,
                                   const u16* __restrict__ adj,
                                   u16* __restrict__ Ohi, int ndst)
{
    constexpr int LANES = D / 8;          // 16B per lane
    constexpr int RPB = 256 / LANES;
    int r = blockIdx.x * RPB + threadIdx.x / LANES;
    if (r >= ndst) return;
    int lane = threadIdx.x % LANES;
    int end = cur[r];
    int n = deg[r];
    int j = end - n;
    float s[8];
    #pragma unroll
    for (int q = 0; q < 8; ++q) s[q] = 0.f;
    for (; j + 1 < end; j += 2) {
        u16x8 a = *(const u16x8*)(Xhi + (size_t)adj[j] * D + lane * 8);
        u16x8 b = *(const u16x8*)(Xhi + (size_t)adj[j + 1] * D + lane * 8);
        #pragma unroll
        for (int q = 0; q < 8; ++q) s[q] += bf2f(a[q]) + bf2f(b[q]);
    }
    if (j < end) {
        u16x8 a = *(const u16x8*)(Xhi + (size_t)adj[j] * D + lane * 8);
        #pragma unroll
        for (int q = 0; q < 8; ++q) s[q] += bf2f(a[q]);
    }
    float inv = (n > 0) ? 1.0f / (float)n : 0.f;
    size_t off = (size_t)r * D + lane * 8;
    u16x8 h8;
    #pragma unroll
    for (int q = 0; q < 8; ++q) h8[q] = f2bf(s[q] * inv);
    *(u16x8*)(Ohi + off) = h8;
}

// ---------------- fused news assembly: N = [relu](N + meanC(PP) + meanD(PP2)) ----------------
template <int D, bool RELU>
__global__ void fuse_news_kernel(const u16* __restrict__ PPh, const u16* __restrict__ PP2h,
                                 const int* __restrict__ curC, const int* __restrict__ degC,
                                 const int* __restrict__ curD, const int* __restrict__ degD,
                                 const u16* __restrict__ adj,
                                 u16* __restrict__ Nh, int ndst)
{
    constexpr int LANES = D / 8;          // 16B per lane
    constexpr int RPB = 256 / LANES;
    int r = blockIdx.x * RPB + threadIdx.x / LANES;
    if (r >= ndst) return;
    int lane = threadIdx.x % LANES;
    float s[8];
    #pragma unroll
    for (int q = 0; q < 8; ++q) s[q] = 0.f;
    {
        int end = curC[r], n = degC[r];
        float a[8];
        #pragma unroll
        for (int q = 0; q < 8; ++q) a[q] = 0.f;
        for (int j = end - n; j < end; ++j) {
            u16x8 v = *(const u16x8*)(PPh + (size_t)adj[j] * D + lane * 8);
            #pragma unroll
            for (int q = 0; q < 8; ++q) a[q] += bf2f(v[q]);
        }
        float inv = (n > 0) ? 1.0f / (float)n : 0.f;
        #pragma unroll
        for (int q = 0; q < 8; ++q) s[q] += a[q] * inv;
    }
    {
        int end = curD[r], n = degD[r];
        float a[8];
        #pragma unroll
        for (int q = 0; q < 8; ++q) a[q] = 0.f;
        for (int j = end - n; j < end; ++j) {
            u16x8 v = *(const u16x8*)(PP2h + (size_t)adj[j] * D + lane * 8);
            #pragma unroll
            for (int q = 0; q < 8; ++q) a[q] += bf2f(v[q]);
        }
        float inv = (n > 0) ? 1.0f / (float)n : 0.f;
        #pragma unroll
        for (int q = 0; q < 8; ++q) s[q] += a[q] * inv;
    }
    size_t off = (size_t)r * D + lane * 8;
    u16x8 h = *(const u16x8*)(Nh + off);
    #pragma unroll
    for (int q = 0; q < 8; ++q) {
        float v = s[q] + bf2f(h[q]);
        if (RELU) v = fmaxf(v, 0.f);
        s[q] = v;
    }
    u16x8 oh;
    #pragma unroll
    for (int q = 0; q < 8; ++q) oh[q] = f2bf(s[q]);
    *(u16x8*)(Nh + off) = oh;
}

// ---------------- batched weight split/convert ----------------
#define MAXJOBS 20
struct SplitJobs {
    const float* a[MAXJOBS];
    const float* b[MAXJOBS];     // optional second operand (summed)
    u16* hi[MAXJOBS];
    u16* lo[MAXJOBS];
    int n[MAXJOBS];
    int ncols[MAXJOBS];          // source row width
    int dstride[MAXJOBS];        // dest row stride
    int boff[MAXJOBS + 1];
    int njobs;
};

__global__ void split_all_kernel(SplitJobs J)
{
    int bid = blockIdx.x;
    int j = 0;
    while (j + 1 < J.njobs && bid >= J.boff[j + 1]) ++j;
    int i = (bid - J.boff[j]) * 1024 + threadIdx.x * 4;
    if (i >= J.n[j]) return;
    float4 v = *(const float4*)(J.a[j] + i);
    if (J.b[j]) {
        float4 w = *(const float4*)(J.b[j] + i);
        v.x += w.x; v.y += w.y; v.z += w.z; v.w += w.w;
    }
    int row = i / J.ncols[j], col = i - row * J.ncols[j];
    size_t d = (size_t)row * J.dstride[j] + col;
    ushort4 h, l;
    split2(v.x, h.x, l.x); split2(v.y, h.y, l.y); split2(v.z, h.z, l.z); split2(v.w, h.w, l.w);
    *(ushort4*)(J.hi[j] + d) = h;
    *(ushort4*)(J.lo[j] + d) = l;
}

__global__ void bias_sum_kernel(const float* __restrict__ b1, const float* __restrict__ b2,
                                float* __restrict__ BS1, float* __restrict__ BS2)
{
    int i = blockIdx.x * 256 + threadIdx.x;
    if (i < 256) BS1[i] = b1[256 + i] + b1[768 + i];
    else if (i < 384) { int j = i - 256; BS2[j] = b2[128 + j] + b2[384 + j]; }
}

// ---------------- launch ----------------
extern "C" void kernel_launch(void* const* d_in, const int* in_sizes, int n_in,
                              void* d_out, int out_size, void* d_ws, size_t ws_size,
                              hipStream_t stream)
{
    const float* x_news = (const float*)d_in[0];
    const float* x_kw   = (const float*)d_in[1];
    const float* x_st   = (const float*)d_in[2];
    const float* Wn = (const float*)d_in[3];  const float* bn = (const float*)d_in[4];
    const float* Wk = (const float*)d_in[5];  const float* bk = (const float*)d_in[6];
    const float* Wst = (const float*)d_in[7]; const float* bs = (const float*)d_in[8];
    const float* W1l = (const float*)d_in[9];  const float* b1 = (const float*)d_in[10];
    const float* W1r = (const float*)d_in[11];
    const float* W2l = (const float*)d_in[12]; const float* b2 = (const float*)d_in[13];
    const float* W2r = (const float*)d_in[14];
    const float* DW1 = (const float*)d_in[15]; const float* Db1 = (const float*)d_in[16];
    const float* DW2 = (const float*)d_in[17]; const float* Db2 = (const float*)d_in[18];
    const int* e_hk_src = (const int*)d_in[19];
    const int* e_hk_dst = (const int*)d_in[20];
    const int* e_hs_src = (const int*)d_in[21];
    const int* e_hs_dst = (const int*)d_in[22];
    const int* l_hk_src = (const int*)d_in[23];
    const int* l_hk_dst = (const int*)d_in[24];
    const int* l_hs_src = (const int*)d_in[25];
    const int* l_hs_dst = (const int*)d_in[26];
    float* out = (float*)d_out;

    // ---- workspace layout (bytes, 16B aligned) ----
    char* base = (char*)d_ws;
    auto alloc = [&](size_t bytes) -> char* {
        char* p = base;
        base += (bytes + 15) & ~(size_t)15;
        return p;
    };
    auto aplane = [&](size_t elems) -> u16* { return (u16*)alloc(elems * 2); };

    u16* HNh = aplane((size_t)N_NEWS * HID);
    u16* HKh = aplane((size_t)N_KW * HID);
    u16* HSh = aplane((size_t)N_ST * HID);
    u16* K1h = aplane((size_t)N_KW * HID);
    u16* S1h = aplane((size_t)N_ST * HID);
    u16* PAh = aplane((size_t)(N_KW + N_ST) * HID);   // 12000 rows (kw | st sections)
    u16* PAl = aplane((size_t)(N_KW + N_ST) * HID);   // PP2 buffer (st projections)
    u16* N1h = aplane((size_t)N_NEWS * HID);
    // weight planes
    u16* WnH = aplane(196608);  u16* WnL = aplane(196608);
    u16* WkH = aplane(32768);   u16* WkL = aplane(32768);
    u16* WsH = aplane(16384);   u16* WsL = aplane(16384);
    u16* CW1KH = aplane(131072); u16* CW1KL = aplane(131072);  // [256][512] W1l0|W1r0
    u16* CW1SH = aplane(131072); u16* CW1SL = aplane(131072);  // [256][512] W1l2|W1r2
    u16* W1l1H = aplane(65536);  u16* W1l1L = aplane(65536);
    u16* W1l3H = aplane(65536);  u16* W1l3L = aplane(65536);
    u16* SW1H = aplane(65536);   u16* SW1L = aplane(65536);    // W1r1+W1r3
    u16* CW2KH = aplane(65536);  u16* CW2KL = aplane(65536);   // [128][512] W2l0|W2r0
    u16* CW2SH = aplane(65536);  u16* CW2SL = aplane(65536);   // [128][512] W2l2|W2r2
    u16* W2l1H = aplane(32768);  u16* W2l1L = aplane(32768);
    u16* W2l3H = aplane(32768);  u16* W2l3L = aplane(32768);
    u16* SW2H = aplane(32768);   u16* SW2L = aplane(32768);    // W2r1+W2r3
    u16* DW1H = aplane(65536);   u16* DW1L = aplane(65536);
    float* BS1 = (float*)alloc(256 * 4);
    float* BS2 = (float*)alloc(128 * 4);
    // int pools
    int* deg = (int*)alloc((size_t)NTOT * 4);
    int* cur = (int*)alloc((size_t)NTOT * 4);
    u16* adj = (u16*)alloc((size_t)2 * (E_HK + E_HS) * 2);
    int* bsum = (int*)alloc(512 * 4);

    // overlays: layer-2 outputs reuse the HN region (dead after layer 1)
    u16* K2h = HNh;
    u16* N2h = K2h + (size_t)N_KW * OUTD;
    u16* S2h = N2h + (size_t)N_NEWS * OUTD;

    // ---- CSR build ----
    hipMemsetAsync(deg, 0, (size_t)NTOT * sizeof(int), stream);
    int etot = E_HK + E_HS;
    count_all_kernel<<<(etot + 255) / 256, 256, 0, stream>>>(e_hk_src, e_hk_dst, e_hs_src, e_hs_dst, deg);
    int nb = (NTOT + 255) / 256; // 438
    scan_block_kernel<<<nb, 256, 0, stream>>>(deg, cur, bsum, NTOT);
    scan2_kernel<<<1, 512, 0, stream>>>(bsum, nb);
    scan_add_kernel<<<nb, 256, 0, stream>>>(cur, bsum, NTOT);
    fill_all_kernel<<<(etot + 255) / 256, 256, 0, stream>>>(e_hk_src, e_hk_dst, e_hs_src, e_hs_dst, cur, adj);

    // ---- batched weight conversion ----
    {
        SplitJobs J{};
        int nj = 0, blocks = 0;
        auto job = [&](const float* a, const float* b, u16* hi, u16* lo, int n, int ncols, int dstride) {
            J.a[nj] = a; J.b[nj] = b; J.hi[nj] = hi; J.lo[nj] = lo;
            J.n[nj] = n; J.ncols[nj] = ncols; J.dstride[nj] = dstride;
            J.boff[nj] = blocks;
            blocks += (n / 4 + 255) / 256;
            ++nj;
        };
        job(Wn, nullptr, WnH, WnL, 196608, 196608, 196608);
        job(Wk, nullptr, WkH, WkL, 32768, 32768, 32768);
        job(Wst, nullptr, WsH, WsL, 16384, 16384, 16384);
        job(W1l + 0 * 65536, nullptr, CW1KH, CW1KL, 65536, 256, 512);
        job(W1r + 0 * 65536, nullptr, CW1KH + 256, CW1KL + 256, 65536, 256, 512);
        job(W1l + 2 * 65536, nullptr, CW1SH, CW1SL, 65536, 256, 512);
        job(W1r + 2 * 65536, nullptr, CW1SH + 256, CW1SL + 256, 65536, 256, 512);
        job(W1l + 1 * 65536, nullptr, W1l1H, W1l1L, 65536, 65536, 65536);
        job(W1l + 3 * 65536, nullptr, W1l3H, W1l3L, 65536, 65536, 65536);
        job(W1r + 1 * 65536, W1r + 3 * 65536, SW1H, SW1L, 65536, 65536, 65536);
        job(W2l + 0 * 32768, nullptr, CW2KH, CW2KL, 32768, 256, 512);
        job(W2r + 0 * 32768, nullptr, CW2KH + 256, CW2KL + 256, 32768, 256, 512);
        job(W2l + 2 * 32768, nullptr, CW2SH, CW2SL, 32768, 256, 512);
        job(W2r + 2 * 32768, nullptr, CW2SH + 256, CW2SL + 256, 32768, 256, 512);
        job(W2l + 1 * 32768, nullptr, W2l1H, W2l1L, 32768, 32768, 32768);
        job(W2l + 3 * 32768, nullptr, W2l3H, W2l3L, 32768, 32768, 32768);
        job(W2r + 1 * 32768, W2r + 3 * 32768, SW2H, SW2L, 32768, 32768, 32768);
        job(DW1, nullptr, DW1H, DW1L, 65536, 65536, 65536);
        J.boff[nj] = blocks;
        J.njobs = nj;
        split_all_kernel<<<blocks, 256, 0, stream>>>(J);
    }
    bias_sum_kernel<<<2, 256, 0, stream>>>(b1, b2, BS1, BS2);

    // ---- GEMM wrappers ----
    // fp32-A projection, full split (3 MFMA), hi-only C
    auto gemmF = [&](const float* A, int lda, const u16* Bh, const u16* Bl, int ldw,
                     const float* bias, u16* Ch, int ldc,
                     int M, int N, int K, int flags) {
        dim3 g((M + 127) / 128, N / 128);
        gemm_kernel<0, 1, 3><<<g, 256, 0, stream>>>(
            A, nullptr, nullptr, nullptr, nullptr, nullptr, nullptr, lda, 0,
            Bh, Bl, ldw, bias, Ch, ldc, nullptr, nullptr, nullptr, M, K, flags);
    };
    // PREC=2 plane GEMM (A hi-only, B full, 2 MFMA), hi-only C
    auto gemmP2 = [&](const u16* Ahp, int lda, const u16* Bh, const u16* Bl, int ldw,
                      const float* bias, u16* Ch, int ldc,
                      int M, int N, int K, int flags) {
        dim3 g((M + 127) / 128, N / 128);
        gemm_kernel<1, 1, 2><<<g, 256, 0, stream>>>(
            nullptr, Ahp, nullptr, nullptr, nullptr, nullptr, nullptr, lda, 0,
            Bh, Bl, ldw, bias, Ch, ldc, nullptr, nullptr, nullptr, M, K, flags);
    };
    // PREC=2 dual-table GEMM (A hi-only, B full), hi-only C
    auto gemm22 = [&](const u16* A1hp, const u16* A2hp, int lda, int kpiv,
                      const u16* Bh, const u16* Bl, int ldw,
                      const float* bias, u16* Ch, int ldc,
                      int M, int N, int K, int flags) {
        dim3 g((M + 127) / 128, N / 128);
        gemm_kernel<2, 1, 2><<<g, 256, 0, stream>>>(
            nullptr, A1hp, nullptr, A2hp, nullptr, nullptr, nullptr, lda, kpiv,
            Bh, Bl, ldw, bias, Ch, ldc, nullptr, nullptr, nullptr, M, K, flags);
    };
    // PREC=1 plane GEMM (1 MFMA), hi-only C
    auto gemmLP = [&](const u16* Ahp, int lda, const u16* Bh, int ldw,
                      const float* bias, u16* Ch, int ldc, int M, int N, int K, int flags) {
        dim3 g((M + 127) / 128, N / 128);
        gemm_kernel<1, 1, 1><<<g, 256, 0, stream>>>(
            nullptr, Ahp, nullptr, nullptr, nullptr, nullptr, nullptr, lda, 0,
            Bh, nullptr, ldw, bias, Ch, ldc, nullptr, nullptr, nullptr, M, K, flags);
    };
    // PREC=1 dual-table GEMM, hi-only C
    auto gemmL2 = [&](const u16* A1hp, const u16* A2hp, int lda, int kpiv,
                      const u16* Bh, int ldw, const float* bias, u16* Ch, int ldc,
                      int M, int N, int K, int flags) {
        dim3 g((M + 127) / 128, N / 128);
        gemm_kernel<2, 1, 1><<<g, 256, 0, stream>>>(
            nullptr, A1hp, nullptr, A2hp, nullptr, nullptr, nullptr, lda, kpiv,
            Bh, nullptr, ldw, bias, Ch, ldc, nullptr, nullptr, nullptr, M, K, flags);
    };
    // PREC=1 fused decoder
    auto gemmD = [&](const u16* A1hp, const u16* A2hp,
                     const int* r1, const int* r2, const u16* Bh,
                     const float* bias, const float* dw2, const float* db2, float* ov) {
        dim3 g((E_LBL + 127) / 128, 1);
        gemm_kernel<2, 2, 1><<<g, 256, 0, stream>>>(
            nullptr, A1hp, nullptr, A2hp, nullptr, r1, r2, 128, 128,
            Bh, nullptr, 256, bias, nullptr, 0, dw2, db2, ov, E_LBL, 256, 0);
    };

    // ---- input projections (fp32 A, full split, hi-only outputs) ----
    gemmF(x_news, F_NEWS, WnH, WnL, F_NEWS, bn, HNh, HID, N_NEWS, HID, F_NEWS, FLAG_RELU);
    gemmF(x_kw,   F_KW,   WkH, WkL, F_KW,   bk, HKh, HID, N_KW,   HID, F_KW,   FLAG_RELU);
    gemmF(x_st,   F_ST,   WsH, WsL, F_ST,   bs, HSh, HID, N_ST,   HID, F_ST,   FLAG_RELU);

    // ---- layer 1 (PREC=2: bf16 activations x full-split weights) ----
    gather_mean_kernel<256><<<(N_KW + N_ST + 7) / 8, 256, 0, stream>>>(
        HNh, cur + OFFA, deg + OFFA, adj, PAh, N_KW + N_ST);
    gemm22(PAh, HKh, HID, 256, CW1KH, CW1KL, 512, b1, K1h, HID, N_KW, HID, 512, FLAG_RELU);
    gemm22(PAh + (size_t)N_KW * HID, HSh, HID, 256,
           CW1SH, CW1SL, 512, b1 + 2 * 256, S1h, HID, N_ST, HID, 512, FLAG_RELU);
    gemmLP(HKh, HID, W1l1H, HID, nullptr, PAh, HID, N_KW, HID, HID, 0);   // PP
    gemmLP(HSh, HID, W1l3H, HID, nullptr, PAl, HID, N_ST, HID, HID, 0);   // PP2
    gemmP2(HNh, HID, SW1H, SW1L, HID, BS1, N1h, HID, N_NEWS, HID, HID, 0);
    fuse_news_kernel<256, true><<<(N_NEWS + 7) / 8, 256, 0, stream>>>(
        PAh, PAl, cur + OFFC, deg + OFFC, cur + OFFD, deg + OFFD, adj, N1h, N_NEWS);

    // ---- layer 2 (PREC=1: hi-only, 1 MFMA) ----
    gather_mean_kernel<256><<<(N_KW + N_ST + 7) / 8, 256, 0, stream>>>(
        N1h, cur + OFFA, deg + OFFA, adj, PAh, N_KW + N_ST);
    gemmL2(PAh, K1h, HID, 256, CW2KH, 512, b2, K2h, OUTD, N_KW, OUTD, 512, 0);
    gemmL2(PAh + (size_t)N_KW * HID, S1h, HID, 256, CW2SH, 512, b2 + 2 * 128, S2h, OUTD, N_ST, OUTD, 512, 0);
    gemmLP(K1h, HID, W2l1H, HID, nullptr, PAh, OUTD, N_KW, OUTD, HID, 0);  // PP (n2)
    gemmLP(S1h, HID, W2l3H, HID, nullptr, PAl, OUTD, N_ST, OUTD, HID, 0);  // PP2 (n2)
    gemmLP(N1h, HID, SW2H, HID, BS2, N2h, OUTD, N_NEWS, OUTD, HID, 0);
    fuse_news_kernel<128, false><<<(N_NEWS + 15) / 16, 256, 0, stream>>>(
        PAh, PAl, cur + OFFC, deg + OFFC, cur + OFFD, deg + OFFD, adj, N2h, N_NEWS);

    // ---- fused decoders (PREC=1) ----
    gemmD(N2h, K2h, l_hk_src, l_hk_dst, DW1H, Db1, DW2, Db2, out);
    gemmD(N2h, S2h, l_hs_src, l_hs_dst, DW1H + 32768, Db1 + 128, DW2 + 128, Db2 + 1, out + E_LBL);
}